// Round 11
// baseline (240.996 us; speedup 1.0000x reference)
//
#include <hip/hip_runtime.h>
#include <stdint.h>
#include <stddef.h>

typedef __attribute__((ext_vector_type(4))) float f32x4;
typedef __attribute__((ext_vector_type(4))) uint32_t u32x4;

#define KDIM 4096
#define NH   128
#define MMEM 50000
#define BFEAT 64
#define MLANES 512
#define NWAVES 3072             // 768 blocks x 4 waves, all co-resident (3/CU)

// ---- K1: per-column screen thresholds + counter reset -----------------------
// ratsq[j] = ((0.5 - b_j)/||w_j||)^2 ; margin<=0 -> -1 (always flag).
// Screen (K2): row passes iff sumsq*1.0002 < min_j ratsq[j]  =>
// |<m,w_j>| <= ||m||*||w_j|| < 0.5 - b_j for all j  => all code bits 0.
__global__ __launch_bounds__(64) void wnorm_kernel(
    const float* __restrict__ W, const float* __restrict__ hb,
    float* __restrict__ ratsq, int* __restrict__ count) {
  const int j    = blockIdx.x;          // 128 columns
  const int lane = threadIdx.x;
  const f32x4* wv = reinterpret_cast<const f32x4*>(W + (size_t)j * KDIM);
  float s = 0.f;
#pragma unroll
  for (int q = 0; q < 16; ++q) {
    f32x4 v = wv[lane + 64 * q];
    s += v[0] * v[0] + v[1] * v[1] + v[2] * v[2] + v[3] * v[3];
  }
  for (int o = 32; o; o >>= 1) s += __shfl_down(s, o, 64);
  if (lane == 0) {
    float margin = 0.5f - hb[j];
    ratsq[j] = (margin > 0.f) ? (margin * margin / s) : -1.f;
    if (j == 0) *count = 0;
  }
}

// ---- K2: row-norm screen, 2-deep row pipeline (R11) -------------------------
// Wave per row; named reg sets a/b so row r+NW's loads fly while row r is
// reduced (counted vmcnt by compiler). 768 blocks co-resident (3/CU).
__global__ __launch_bounds__(256, 3) void rowscreen_kernel(
    const float* __restrict__ A, const float* __restrict__ ratsq,
    int* __restrict__ count, int* __restrict__ list,
    u32x4* __restrict__ hm_bits) {
  __shared__ float rs[NH];
  const int t = threadIdx.x;
  if (t < NH) rs[t] = ratsq[t];
  __syncthreads();
  float minrat = rs[0];
#pragma unroll
  for (int j = 1; j < NH; ++j) minrat = fminf(minrat, rs[j]);

  const int gw   = blockIdx.x * 4 + (t >> 6);   // global wave id, 3072 waves
  const int lane = t & 63;

  f32x4 a[16], b[16];

#define LOADROW(DST, R) do {                                                  \
  const f32x4* rv = reinterpret_cast<const f32x4*>(A + (size_t)(R) * KDIM);   \
  _Pragma("unroll")                                                           \
  for (int q = 0; q < 16; ++q) DST[q] = rv[lane + 64 * q];                    \
} while (0)

#define SCREEN(SRC, R) do {                                                   \
  float s0 = 0.f, s1 = 0.f;                                                   \
  _Pragma("unroll")                                                           \
  for (int q = 0; q < 16; q += 2) {                                           \
    s0 += SRC[q][0] * SRC[q][0] + SRC[q][1] * SRC[q][1]                       \
        + SRC[q][2] * SRC[q][2] + SRC[q][3] * SRC[q][3];                      \
    s1 += SRC[q+1][0] * SRC[q+1][0] + SRC[q+1][1] * SRC[q+1][1]               \
        + SRC[q+1][2] * SRC[q+1][2] + SRC[q+1][3] * SRC[q+1][3];              \
  }                                                                           \
  float s = s0 + s1;                                                          \
  for (int o = 32; o; o >>= 1) s += __shfl_down(s, o, 64);                    \
  if (lane == 0) {                                                            \
    if (s * 1.0002f < minrat) {                                               \
      hm_bits[R] = (u32x4){0u, 0u, 0u, 0u};                                   \
    } else {                                                                  \
      int i = atomicAdd(count, 1);                                            \
      list[i] = (R);                                                          \
    }                                                                         \
  }                                                                           \
} while (0)

  int r0 = gw;
  if (r0 < MMEM) LOADROW(a, r0);
  for (; r0 < MMEM; r0 += 2 * NWAVES) {
    const int r1 = r0 + NWAVES;
    if (r1 < MMEM) LOADROW(b, r1);
    SCREEN(a, r0);
    const int r2 = r0 + 2 * NWAVES;
    if (r2 < MMEM) LOADROW(a, r2);
    if (r1 < MMEM) SCREEN(b, r1);
  }

#undef LOADROW
#undef SCREEN
}

// ---- K3: exact f32 fallback for flagged rows (grid-stride; ~0 rows here) ----
__global__ __launch_bounds__(512) void exact_kernel(
    const float* __restrict__ A, const float* __restrict__ W,
    const float* __restrict__ hb, const int* __restrict__ count,
    const int* __restrict__ list, uint32_t* __restrict__ hm_bits) {
  __shared__ unsigned short sb[8];
  const int w    = threadIdx.x >> 6;
  const int lane = threadIdx.x & 63;
  const int cnt  = *count;
  for (int i = blockIdx.x; i < cnt; i += gridDim.x) {
    const int row = list[i];
    const f32x4* rv = reinterpret_cast<const f32x4*>(A + (size_t)row * KDIM);
    unsigned short bits = 0;
    for (int d = 0; d < 16; ++d) {
      const int n = w * 16 + d;
      const f32x4* wv = reinterpret_cast<const f32x4*>(W + (size_t)n * KDIM);
      float s = 0.f;
#pragma unroll 4
      for (int q = 0; q < 16; ++q) {
        f32x4 x = rv[lane + 64 * q], y = wv[lane + 64 * q];
        s += x[0] * y[0] + x[1] * y[1] + x[2] * y[2] + x[3] * y[3];
      }
      for (int o = 32; o; o >>= 1) s += __shfl_down(s, o, 64);
      s = __shfl(s, 0, 64);
      if (s + hb[n] - 0.5f > 0.f) bits |= (unsigned short)(1u << d);
    }
    if (lane == 0) sb[w] = bits;
    __syncthreads();
    if (threadIdx.x < 4) {
      uint32_t word = (uint32_t)sb[2 * threadIdx.x] |
                      ((uint32_t)sb[2 * threadIdx.x + 1] << 16);
      hm_bits[(size_t)row * 4 + threadIdx.x] = word;
    }
    __syncthreads();
  }
}

// ---- K4: inline hf + per-batch argmin Hamming + fused gather (validated) ----
__global__ __launch_bounds__(512) void argmin_gather_kernel(
    const uint32_t* __restrict__ hm_bits, const float* __restrict__ feature,
    const float* __restrict__ Wf, const float* __restrict__ hb,
    const float* __restrict__ memory, float* __restrict__ out) {
  __shared__ unsigned char hfb[NH];
  __shared__ uint32_t red[MLANES];
  const int b    = blockIdx.x;
  const int t    = threadIdx.x;
  const int w    = t >> 6;
  const int lane = t & 63;

  // ---- inline hf: 16 f32 dots per wave ----
  const f32x4* fv = reinterpret_cast<const f32x4*>(feature + (size_t)b * KDIM);
#pragma unroll 2
  for (int d = 0; d < 16; ++d) {
    const int n = w * 16 + d;
    const f32x4* wv = reinterpret_cast<const f32x4*>(Wf + (size_t)n * KDIM);
    float s = 0.f;
#pragma unroll 4
    for (int q = 0; q < 16; ++q) {
      f32x4 x = fv[lane + 64 * q], y = wv[lane + 64 * q];
      s += x[0] * y[0] + x[1] * y[1] + x[2] * y[2] + x[3] * y[3];
    }
    for (int o = 32; o; o >>= 1) s += __shfl_down(s, o, 64);
    if (lane == 0) hfb[n] = (s + hb[n] - 0.5f) > 0.f ? 1 : 0;
  }
  __syncthreads();

  uint64_t hf0 = 0, hf1 = 0;
  for (int c = 0; c < 64; ++c) {
    hf0 |= (uint64_t)(hfb[c] & 1u) << c;
    hf1 |= (uint64_t)(hfb[c + 64] & 1u) << c;
  }
  int hfsum = __popcll(hf0) + __popcll(hf1);
  uint32_t best = 0xFFFFFFFFu;
  for (int m = t; m < MMEM; m += MLANES) {
    u32x4 pv = reinterpret_cast<const u32x4*>(hm_bits)[m];
    uint64_t h0 = (uint64_t)pv[0] | ((uint64_t)pv[1] << 32);
    uint64_t h1 = (uint64_t)pv[2] | ((uint64_t)pv[3] << 32);
    int hmsum = __popcll(h0) + __popcll(h1);
    int dot   = __popcll(h0 & hf0) + __popcll(h1 & hf1);
    int hd    = hfsum + hmsum - 2 * dot;
    uint32_t key = ((uint32_t)hd << 16) | (uint32_t)m;   // M < 65536, HD <= 256
    best = best < key ? best : key;
  }
  red[t] = best;
  __syncthreads();
  for (int s = MLANES / 2; s > 0; s >>= 1) {
    if (t < s) red[t] = red[t] < red[t + s] ? red[t] : red[t + s];
    __syncthreads();
  }
  const int m = (int)(red[0] & 0xFFFFu);
  const f32x4* src = reinterpret_cast<const f32x4*>(memory + (size_t)m * KDIM);
  f32x4* dst = reinterpret_cast<f32x4*>(out + (size_t)b * KDIM);
  dst[t]       = src[t];
  dst[t + 512] = src[t + 512];
}

extern "C" void kernel_launch(void* const* d_in, const int* in_sizes, int n_in,
                              void* d_out, int out_size, void* d_ws, size_t ws_size,
                              hipStream_t stream) {
  const float* feature = (const float*)d_in[0];   // [64,64,8,8] == [64,4096]
  const float* memory  = (const float*)d_in[1];   // [50000,4096]
  const float* hash_W  = (const float*)d_in[2];   // [128,4096]
  const float* hash_b  = (const float*)d_in[3];   // [128]
  float* out = (float*)d_out;

  char* ws = (char*)d_ws;
  uint32_t* hm_bits = (uint32_t*)ws;                    //   800,000 B
  float*    ratsq   = (float*)(ws + 800000);            //       512 B
  int*      count   = (int*)(ws + 800512);              //         4 B
  int*      list    = (int*)(ws + 800768);              //   200,000 B

  wnorm_kernel<<<NH, 64, 0, stream>>>(hash_W, hash_b, ratsq, count);
  rowscreen_kernel<<<768, 256, 0, stream>>>(memory, ratsq, count, list,
                                            (u32x4*)hm_bits);
  exact_kernel<<<128, 512, 0, stream>>>(memory, hash_W, hash_b, count, list,
                                        hm_bits);
  argmin_gather_kernel<<<BFEAT, 512, 0, stream>>>(hm_bits, feature, hash_W,
                                                  hash_b, memory, out);
}

// Round 12
// 225.943 us; speedup vs baseline: 1.0666x; 1.0666x over previous
//
#include <hip/hip_runtime.h>
#include <hip/hip_bf16.h>
#include <stdint.h>
#include <stddef.h>

typedef __attribute__((ext_vector_type(8))) short s8v;       // 8 x bf16 (as i16)
typedef __attribute__((ext_vector_type(4))) float f32x4;
typedef __attribute__((ext_vector_type(4))) uint32_t u32x4;
typedef __attribute__((ext_vector_type(4))) unsigned short u16x4;

#define KDIM 4096
#define NH   128
#define MMEM 50000
#define BFEAT 64
#define NGRP 3125               // 50000 / 16 row-groups, exact
#define NBLK 256                // one block per CU, perfect balance (R7-validated)
#define NGMAX 13                // max groups per block (53 blocks have 13, rest 12)
#define MLANES 512

static __device__ __forceinline__ unsigned short f2bf(float f) {
  union { float f; uint32_t u; } c; c.f = f;
  uint32_t u = c.u;
  return (unsigned short)((u + 0x7FFFu + ((u >> 16) & 1u)) >> 16);  // RNE
}

static __device__ __forceinline__ short f2bfs(float f) {
  __hip_bfloat16 h = __float2bfloat16(f);   // pairs fuse to v_cvt_pk_bf16_f32
  short s;
  __builtin_memcpy(&s, &h, sizeof(s));
  return s;
}

// ---- Kernel 0: hash_W f32 -> bf16 (convert only; hf moved to argmin) --------
__global__ __launch_bounds__(256) void convert_w_kernel(
    const float* __restrict__ W, unsigned short* __restrict__ Wb) {
  int i = blockIdx.x * 256 + threadIdx.x;          // float4 index, 131072 total
  f32x4 v = reinterpret_cast<const f32x4*>(W)[i];
  u16x4 o;
  o[0] = f2bf(v[0]); o[1] = f2bf(v[1]); o[2] = f2bf(v[2]); o[3] = f2bf(v[3]);
  reinterpret_cast<u16x4*>(Wb)[i] = o;
}

// ---- Kernel A: persistent balanced streaming MFMA (R7 structure, EXACT) -----
// 256 blocks x 512 threads, block owns 12-13 groups of 16 rows, acc resident.
// K-phase stagger koff = b & 63 (R7, validated +8%): spreads the instantaneous
// address stream over all 64 k-windows -> all HBM channels active.
// Sync: lgkmcnt(0) + raw s_barrier only (no vmcnt drain; compiler counts).

__global__ __launch_bounds__(512, 2) void hash_bits_kernel(
    const float* __restrict__ A,
    const unsigned short* __restrict__ Wb,
    const float* __restrict__ hb,
    uint32_t* __restrict__ out_bits) {
  __shared__ short Abuf[2][NGMAX * 16 * 64];       // 2 x 26 KB bf16, swizzled
  __shared__ unsigned short smb[NGMAX * 16][8];    // epilogue u16 slices

  const int t    = threadIdx.x;
  const int lane = t & 63;
  const int w    = t >> 6;          // wave 0..7 -> cols 16w..16w+15
  const int l15  = lane & 15;
  const int kq   = lane >> 4;
  const int b    = blockIdx.x;
  const int koff = b & 63;          // K-phase stagger
  const int g0   = (b * NGRP) >> 8;
  const int NG   = (((b + 1) * NGRP) >> 8) - g0;   // 12 or 13
  const int row0 = g0 * 16;

  // ---- staging geometry: slot P = t + 512p -> 32B of one row ----
  const float* srcA[4];
  int ldsoff[4];
#pragma unroll
  for (int p = 0; p < 4; ++p) {
    int P  = t + 512 * p;
    int g  = P >> 7;
    int q  = P & 127;
    int r  = q >> 3;
    int kg = q & 7;
    srcA[p]   = A + (size_t)(row0 + g * 16 + r) * KDIM + kg * 8;
    ldsoff[p] = (g * 16 + r) * 64 + ((kg ^ (r & 7)) << 3);
  }
  const bool v3 = (t + 1536) < NG * 128;   // p=3 validity (p<3 always valid)

  const unsigned short* pb = Wb + (size_t)(16 * w + l15) * KDIM + kq * 8;
  const float hbv = hb[16 * w + l15];

  f32x4 acc[NGMAX];
#pragma unroll
  for (int g = 0; g < NGMAX; ++g) acc[g] = (f32x4){0.f, 0.f, 0.f, 0.f};

  f32x4 aR[4][2];
  s8v bA0, bA1, bB0, bB1;    // B-frag ring x2 (static regs, rule #20)

#define PCH(S) (((S) + koff) & 63)   // logical step -> physical chunk

#define LOADA(CH) do {                                                        \
  const f32x4* q0 = reinterpret_cast<const f32x4*>(srcA[0] + (CH) * 64);      \
  aR[0][0] = q0[0]; aR[0][1] = q0[1];                                         \
  const f32x4* q1 = reinterpret_cast<const f32x4*>(srcA[1] + (CH) * 64);      \
  aR[1][0] = q1[0]; aR[1][1] = q1[1];                                         \
  const f32x4* q2 = reinterpret_cast<const f32x4*>(srcA[2] + (CH) * 64);      \
  aR[2][0] = q2[0]; aR[2][1] = q2[1];                                         \
  if (v3) {                                                                   \
    const f32x4* q3 = reinterpret_cast<const f32x4*>(srcA[3] + (CH) * 64);    \
    aR[3][0] = q3[0]; aR[3][1] = q3[1];                                       \
  }                                                                           \
} while (0)

#define CVTW1(P, BUFW) do {                                                   \
  s8v av;                                                                     \
  av[0] = f2bfs(aR[P][0][0]); av[1] = f2bfs(aR[P][0][1]);                     \
  av[2] = f2bfs(aR[P][0][2]); av[3] = f2bfs(aR[P][0][3]);                     \
  av[4] = f2bfs(aR[P][1][0]); av[5] = f2bfs(aR[P][1][1]);                     \
  av[6] = f2bfs(aR[P][1][2]); av[7] = f2bfs(aR[P][1][3]);                     \
  *reinterpret_cast<s8v*>(&(BUFW)[ldsoff[P]]) = av;                           \
} while (0)

#define CVTWRITE(BUFW) do {                                                   \
  CVTW1(0, BUFW); CVTW1(1, BUFW); CVTW1(2, BUFW);                             \
  if (v3) CVTW1(3, BUFW);                                                     \
} while (0)

#define LOADB(CH, B0, B1) do {                                                \
  B0 = *reinterpret_cast<const s8v*>(pb + (CH) * 64);                         \
  B1 = *reinterpret_cast<const s8v*>(pb + (CH) * 64 + 32);                    \
} while (0)

#define COMPUTE(BUFR, B0, B1) do {                                            \
  _Pragma("unroll")                                                           \
  for (int g = 0; g < NGMAX; ++g) {                                           \
    const s8v af = *reinterpret_cast<const s8v*>(                             \
        &(BUFR)[(g * 16 + l15) * 64 + ((kq ^ (l15 & 7)) << 3)]);              \
    acc[g] = __builtin_amdgcn_mfma_f32_16x16x32_bf16(af, B0, acc[g], 0, 0, 0);\
  }                                                                           \
  _Pragma("unroll")                                                           \
  for (int g = 0; g < NGMAX; ++g) {                                           \
    const s8v af = *reinterpret_cast<const s8v*>(                             \
        &(BUFR)[(g * 16 + l15) * 64 + (((4 + kq) ^ (l15 & 7)) << 3)]);        \
    acc[g] = __builtin_amdgcn_mfma_f32_16x16x32_bf16(af, B1, acc[g], 0, 0, 0);\
  }                                                                           \
} while (0)

#define BARRIER() do {                                                        \
  asm volatile("s_waitcnt lgkmcnt(0)" ::: "memory");                          \
  __builtin_amdgcn_s_barrier();                                               \
  __builtin_amdgcn_sched_barrier(0);                                          \
} while (0)

// One pipeline step, logical chunk S: barrier | compute S | cvt+write S+1 | issue S+2
#define STEP(S, BUFR, BUFW, B0, B1) do {                                      \
  BARRIER();                                                                  \
  COMPUTE(BUFR, B0, B1);                                                      \
  if ((S) + 1 < 64) CVTWRITE(BUFW);                                           \
  if ((S) + 2 < 64) { LOADA(PCH((S) + 2)); LOADB(PCH((S) + 2), B0, B1); }     \
} while (0)

  // Prologue: A(0) -> LDS buf0; A(1) -> regs; B(0),B(1) -> reg sets
  LOADA(PCH(0));
  CVTWRITE(Abuf[0]);
  LOADA(PCH(1));
  LOADB(PCH(0), bA0, bA1);
  LOADB(PCH(1), bB0, bB1);

  for (int s2 = 0; s2 < 64; s2 += 2) {
    STEP(s2 + 0, Abuf[0], Abuf[1], bA0, bA1);
    STEP(s2 + 1, Abuf[1], Abuf[0], bB0, bB1);
  }

  // ---- epilogue: sign -> ballot -> u16 slices -> packed 128-bit rows ----
#pragma unroll
  for (int g = 0; g < NGMAX; ++g) {
#pragma unroll
    for (int r = 0; r < 4; ++r) {
      uint64_t mask = __ballot(acc[g][r] + hbv - 0.5f > 0.f);
      if (l15 == r)
        smb[g * 16 + (lane >> 4) * 4 + r][w] =
            (unsigned short)((mask >> (16 * (lane >> 4))) & 0xFFFFu);
    }
  }
  __syncthreads();
  const int rows = NG * 16;
  if (t < rows) {
    uint32_t w0 = (uint32_t)smb[t][0] | ((uint32_t)smb[t][1] << 16);
    uint32_t w1 = (uint32_t)smb[t][2] | ((uint32_t)smb[t][3] << 16);
    uint32_t w2 = (uint32_t)smb[t][4] | ((uint32_t)smb[t][5] << 16);
    uint32_t w3 = (uint32_t)smb[t][6] | ((uint32_t)smb[t][7] << 16);
    reinterpret_cast<u32x4*>(out_bits)[row0 + t] = (u32x4){w0, w1, w2, w3};
  }
}

// ---- Kernel B: inline hf + per-batch argmin Hamming + fused gather ----------
// (validated R9-R11) 64 blocks x 512 threads; block owns one batch row.
__global__ __launch_bounds__(512) void argmin_gather_kernel(
    const uint32_t* __restrict__ hm_bits, const float* __restrict__ feature,
    const float* __restrict__ Wf, const float* __restrict__ hb,
    const float* __restrict__ memory, float* __restrict__ out) {
  __shared__ unsigned char hfb[NH];
  __shared__ uint32_t red[MLANES];
  const int b    = blockIdx.x;
  const int t    = threadIdx.x;
  const int w    = t >> 6;
  const int lane = t & 63;

  // ---- inline hf: 16 f32 dots per wave ----
  const f32x4* fv = reinterpret_cast<const f32x4*>(feature + (size_t)b * KDIM);
#pragma unroll 2
  for (int d = 0; d < 16; ++d) {
    const int n = w * 16 + d;
    const f32x4* wv = reinterpret_cast<const f32x4*>(Wf + (size_t)n * KDIM);
    float s = 0.f;
#pragma unroll 4
    for (int q = 0; q < 16; ++q) {
      f32x4 x = fv[lane + 64 * q], y = wv[lane + 64 * q];
      s += x[0] * y[0] + x[1] * y[1] + x[2] * y[2] + x[3] * y[3];
    }
    for (int o = 32; o; o >>= 1) s += __shfl_down(s, o, 64);
    if (lane == 0) hfb[n] = (s + hb[n] - 0.5f) > 0.f ? 1 : 0;
  }
  __syncthreads();

  uint64_t hf0 = 0, hf1 = 0;
  for (int c = 0; c < 64; ++c) {
    hf0 |= (uint64_t)(hfb[c] & 1u) << c;
    hf1 |= (uint64_t)(hfb[c + 64] & 1u) << c;
  }
  int hfsum = __popcll(hf0) + __popcll(hf1);
  uint32_t best = 0xFFFFFFFFu;
  for (int m = t; m < MMEM; m += MLANES) {
    u32x4 pv = reinterpret_cast<const u32x4*>(hm_bits)[m];
    uint64_t h0 = (uint64_t)pv[0] | ((uint64_t)pv[1] << 32);
    uint64_t h1 = (uint64_t)pv[2] | ((uint64_t)pv[3] << 32);
    int hmsum = __popcll(h0) + __popcll(h1);
    int dot   = __popcll(h0 & hf0) + __popcll(h1 & hf1);
    int hd    = hfsum + hmsum - 2 * dot;
    uint32_t key = ((uint32_t)hd << 16) | (uint32_t)m;   // M < 65536, HD <= 256
    best = best < key ? best : key;
  }
  red[t] = best;
  __syncthreads();
  for (int s = MLANES / 2; s > 0; s >>= 1) {
    if (t < s) red[t] = red[t] < red[t + s] ? red[t] : red[t + s];
    __syncthreads();
  }
  const int m = (int)(red[0] & 0xFFFFu);
  const f32x4* src = reinterpret_cast<const f32x4*>(memory + (size_t)m * KDIM);
  f32x4* dst = reinterpret_cast<f32x4*>(out + (size_t)b * KDIM);
  dst[t]       = src[t];
  dst[t + 512] = src[t + 512];
}

extern "C" void kernel_launch(void* const* d_in, const int* in_sizes, int n_in,
                              void* d_out, int out_size, void* d_ws, size_t ws_size,
                              hipStream_t stream) {
  const float* feature = (const float*)d_in[0];   // [64,64,8,8] == [64,4096]
  const float* memory  = (const float*)d_in[1];   // [50000,4096]
  const float* hash_W  = (const float*)d_in[2];   // [128,4096]
  const float* hash_b  = (const float*)d_in[3];   // [128]
  float* out = (float*)d_out;

  char* ws = (char*)d_ws;
  unsigned short* Wb      = (unsigned short*)ws;          // 1,048,576 B
  uint32_t*       hm_bits = (uint32_t*)(ws + 1048576);    //   800,000 B

  convert_w_kernel<<<512, 256, 0, stream>>>(hash_W, Wb);
  hash_bits_kernel<<<NBLK, 512, 0, stream>>>(memory, Wb, hash_b, hm_bits);
  argmin_gather_kernel<<<BFEAT, 512, 0, stream>>>(hm_bits, feature, hash_W,
                                                  hash_b, memory, out);
}

// Round 13
// 174.596 us; speedup vs baseline: 1.3803x; 1.2941x over previous
//
#include <hip/hip_runtime.h>
#include <hip/hip_bf16.h>
#include <stdint.h>
#include <stddef.h>

typedef __attribute__((ext_vector_type(8))) short s8v;       // 8 x bf16 (as i16)
typedef __attribute__((ext_vector_type(4))) float f32x4;
typedef __attribute__((ext_vector_type(4))) uint32_t u32x4;
typedef __attribute__((ext_vector_type(4))) unsigned short u16x4;

#define KDIM 4096
#define NH   128
#define MMEM 50000
#define BFEAT 64
#define NGRP 3125               // 50000 / 16 row-groups, exact
#define NBLK 256                // one block per CU, perfect balance
#define NGMAX 13                // max groups per block (53 blocks have 13, rest 12)
#define NSEG 8                  // argmin M-segments

static __device__ __forceinline__ unsigned short f2bf(float f) {
  union { float f; uint32_t u; } c; c.f = f;
  uint32_t u = c.u;
  return (unsigned short)((u + 0x7FFFu + ((u >> 16) & 1u)) >> 16);  // RNE
}

static __device__ __forceinline__ short f2bfs(float f) {
  __hip_bfloat16 h = __float2bfloat16(f);   // pairs fuse to v_cvt_pk_bf16_f32
  short s;
  __builtin_memcpy(&s, &h, sizeof(s));
  return s;
}

// ---- Kernel 0 (fused): hash_W f32->bf16  |  hf feature codes  |  keys init --
__global__ __launch_bounds__(256) void prep_kernel(
    const float* __restrict__ W, unsigned short* __restrict__ Wb,
    const float* __restrict__ flat, const float* __restrict__ hb,
    unsigned char* __restrict__ hf_bytes, unsigned int* __restrict__ keys) {
  const int bid = blockIdx.x;
  const int t   = threadIdx.x;
  if (bid < 512) {                      // ---- convert part: 512 blocks ----
    if (bid == 0 && t < BFEAT) keys[t] = 0xFFFFFFFFu;
    int i = bid * 256 + t;              // float4 index, 131072 total
    f32x4 v = reinterpret_cast<const f32x4*>(W)[i];
    u16x4 o;
    o[0] = f2bf(v[0]); o[1] = f2bf(v[1]); o[2] = f2bf(v[2]); o[3] = f2bf(v[3]);
    reinterpret_cast<u16x4*>(Wb)[i] = o;
  } else {                              // ---- hf part: 2048 blocks x 4 dots ----
    int did  = (bid - 512) * 4 + (t >> 6);   // 8192 dots
    int n = did & 127, b = did >> 7;
    int lane = t & 63;
    const f32x4* fa = reinterpret_cast<const f32x4*>(flat + (size_t)b * KDIM);
    const f32x4* wa = reinterpret_cast<const f32x4*>(W + (size_t)n * KDIM);
    float s = 0.f;
#pragma unroll 4
    for (int q = 0; q < 16; ++q) {
      f32x4 x = fa[lane + 64 * q], y = wa[lane + 64 * q];
      s += x[0] * y[0] + x[1] * y[1] + x[2] * y[2] + x[3] * y[3];
    }
    for (int o = 32; o; o >>= 1) s += __shfl_down(s, o, 64);
    if (lane == 0) hf_bytes[b * NH + n] = (s + hb[n] - 0.5f) > 0.f ? 1 : 0;
  }
}

// ---- Kernel A: persistent balanced streaming MFMA (R5 structure) ------------
// 256 blocks x 512 threads, block owns 12-13 groups of 16 rows, acc resident.
// K-phase offset koff = b & 63 de-phases the K-sweep across blocks so the
// instantaneous address stream covers all 64 k-windows (HBM channel spread).
// Sync: lgkmcnt(0) + raw s_barrier only (no vmcnt drain; compiler counts).

__global__ __launch_bounds__(512, 2) void hash_bits_kernel(
    const float* __restrict__ A,
    const unsigned short* __restrict__ Wb,
    const float* __restrict__ hb,
    uint32_t* __restrict__ out_bits) {
  __shared__ short Abuf[2][NGMAX * 16 * 64];       // 2 x 26 KB bf16, swizzled
  __shared__ unsigned short smb[NGMAX * 16][8];    // epilogue u16 slices

  const int t    = threadIdx.x;
  const int lane = t & 63;
  const int w    = t >> 6;          // wave 0..7 -> cols 16w..16w+15
  const int l15  = lane & 15;
  const int kq   = lane >> 4;
  const int b    = blockIdx.x;
  const int koff = b & 63;          // K-phase stagger
  const int g0   = (b * NGRP) >> 8;
  const int NG   = (((b + 1) * NGRP) >> 8) - g0;   // 12 or 13
  const int row0 = g0 * 16;

  // ---- staging geometry: pair P = t + 512p -> 32B of one row ----
  const float* srcA[4];
  int ldsoff[4];
#pragma unroll
  for (int p = 0; p < 4; ++p) {
    int P  = t + 512 * p;
    int g  = P >> 7;
    int q  = P & 127;
    int r  = q >> 3;
    int kg = q & 7;
    srcA[p]   = A + (size_t)(row0 + g * 16 + r) * KDIM + kg * 8;
    ldsoff[p] = (g * 16 + r) * 64 + ((kg ^ (r & 7)) << 3);
  }
  const bool v3 = (t + 1536) < NG * 128;   // p=3 validity (p<3 always valid)

  const unsigned short* pb = Wb + (size_t)(16 * w + l15) * KDIM + kq * 8;
  const float hbv = hb[16 * w + l15];

  f32x4 acc[NGMAX];
#pragma unroll
  for (int g = 0; g < NGMAX; ++g) acc[g] = (f32x4){0.f, 0.f, 0.f, 0.f};

  f32x4 aR[4][2];
  s8v bA0, bA1, bB0, bB1;    // B-frag ring x2 (static regs, rule #20)

#define PCH(S) (((S) + koff) & 63)   // logical step -> physical chunk

#define LOADA(CH) do {                                                        \
  const f32x4* q0 = reinterpret_cast<const f32x4*>(srcA[0] + (CH) * 64);      \
  aR[0][0] = q0[0]; aR[0][1] = q0[1];                                         \
  const f32x4* q1 = reinterpret_cast<const f32x4*>(srcA[1] + (CH) * 64);      \
  aR[1][0] = q1[0]; aR[1][1] = q1[1];                                         \
  const f32x4* q2 = reinterpret_cast<const f32x4*>(srcA[2] + (CH) * 64);      \
  aR[2][0] = q2[0]; aR[2][1] = q2[1];                                         \
  if (v3) {                                                                   \
    const f32x4* q3 = reinterpret_cast<const f32x4*>(srcA[3] + (CH) * 64);    \
    aR[3][0] = q3[0]; aR[3][1] = q3[1];                                       \
  }                                                                           \
} while (0)

#define CVTW1(P, BUFW) do {                                                   \
  s8v av;                                                                     \
  av[0] = f2bfs(aR[P][0][0]); av[1] = f2bfs(aR[P][0][1]);                     \
  av[2] = f2bfs(aR[P][0][2]); av[3] = f2bfs(aR[P][0][3]);                     \
  av[4] = f2bfs(aR[P][1][0]); av[5] = f2bfs(aR[P][1][1]);                     \
  av[6] = f2bfs(aR[P][1][2]); av[7] = f2bfs(aR[P][1][3]);                     \
  *reinterpret_cast<s8v*>(&(BUFW)[ldsoff[P]]) = av;                           \
} while (0)

#define CVTWRITE(BUFW) do {                                                   \
  CVTW1(0, BUFW); CVTW1(1, BUFW); CVTW1(2, BUFW);                             \
  if (v3) CVTW1(3, BUFW);                                                     \
} while (0)

#define LOADB(CH, B0, B1) do {                                                \
  B0 = *reinterpret_cast<const s8v*>(pb + (CH) * 64);                         \
  B1 = *reinterpret_cast<const s8v*>(pb + (CH) * 64 + 32);                    \
} while (0)

#define COMPUTE(BUFR, B0, B1) do {                                            \
  _Pragma("unroll")                                                           \
  for (int g = 0; g < NGMAX; ++g) {                                           \
    const s8v af = *reinterpret_cast<const s8v*>(                             \
        &(BUFR)[(g * 16 + l15) * 64 + ((kq ^ (l15 & 7)) << 3)]);              \
    acc[g] = __builtin_amdgcn_mfma_f32_16x16x32_bf16(af, B0, acc[g], 0, 0, 0);\
  }                                                                           \
  _Pragma("unroll")                                                           \
  for (int g = 0; g < NGMAX; ++g) {                                           \
    const s8v af = *reinterpret_cast<const s8v*>(                             \
        &(BUFR)[(g * 16 + l15) * 64 + (((4 + kq) ^ (l15 & 7)) << 3)]);        \
    acc[g] = __builtin_amdgcn_mfma_f32_16x16x32_bf16(af, B1, acc[g], 0, 0, 0);\
  }                                                                           \
} while (0)

#define BARRIER() do {                                                        \
  asm volatile("s_waitcnt lgkmcnt(0)" ::: "memory");                          \
  __builtin_amdgcn_s_barrier();                                               \
  __builtin_amdgcn_sched_barrier(0);                                          \
} while (0)

// One pipeline step, logical chunk S: barrier | compute S | cvt+write S+1 | issue S+2
#define STEP(S, BUFR, BUFW, B0, B1) do {                                      \
  BARRIER();                                                                  \
  COMPUTE(BUFR, B0, B1);                                                      \
  if ((S) + 1 < 64) CVTWRITE(BUFW);                                           \
  if ((S) + 2 < 64) { LOADA(PCH((S) + 2)); LOADB(PCH((S) + 2), B0, B1); }     \
} while (0)

  // Prologue: A(0) -> LDS buf0; A(1) -> regs; B(0),B(1) -> reg sets
  LOADA(PCH(0));
  CVTWRITE(Abuf[0]);
  LOADA(PCH(1));
  LOADB(PCH(0), bA0, bA1);
  LOADB(PCH(1), bB0, bB1);

  for (int s2 = 0; s2 < 64; s2 += 2) {
    STEP(s2 + 0, Abuf[0], Abuf[1], bA0, bA1);
    STEP(s2 + 1, Abuf[1], Abuf[0], bB0, bB1);
  }

  // ---- epilogue: sign -> ballot -> u16 slices -> packed 128-bit rows ----
#pragma unroll
  for (int g = 0; g < NGMAX; ++g) {
#pragma unroll
    for (int r = 0; r < 4; ++r) {
      uint64_t mask = __ballot(acc[g][r] + hbv - 0.5f > 0.f);
      if (l15 == r)
        smb[g * 16 + (lane >> 4) * 4 + r][w] =
            (unsigned short)((mask >> (16 * (lane >> 4))) & 0xFFFFu);
    }
  }
  __syncthreads();
  const int rows = NG * 16;
  if (t < rows) {
    uint32_t w0 = (uint32_t)smb[t][0] | ((uint32_t)smb[t][1] << 16);
    uint32_t w1 = (uint32_t)smb[t][2] | ((uint32_t)smb[t][3] << 16);
    uint32_t w2 = (uint32_t)smb[t][4] | ((uint32_t)smb[t][5] << 16);
    uint32_t w3 = (uint32_t)smb[t][6] | ((uint32_t)smb[t][7] << 16);
    reinterpret_cast<u32x4*>(out_bits)[row0 + t] = (u32x4){w0, w1, w2, w3};
  }
}

// ---- Kernel B: segmented argmin Hamming (ref tie-break) via atomicMin -------
__global__ __launch_bounds__(256) void argmin_part_kernel(
    const uint32_t* __restrict__ hm_bits, const unsigned char* __restrict__ hf_bytes,
    int M, unsigned int* __restrict__ keys) {
  __shared__ uint32_t red[256];
  const int b   = blockIdx.x & (BFEAT - 1);
  const int seg = blockIdx.x / BFEAT;
  const int span = (M + NSEG - 1) / NSEG;
  const int m0 = seg * span;
  int m1 = m0 + span; if (m1 > M) m1 = M;
  const int t = threadIdx.x;
  uint64_t hf0 = 0, hf1 = 0;
  const unsigned char* hfb = hf_bytes + b * NH;
  for (int c = 0; c < 64; ++c) {
    hf0 |= (uint64_t)(hfb[c] & 1u) << c;
    hf1 |= (uint64_t)(hfb[c + 64] & 1u) << c;
  }
  int hfsum = __popcll(hf0) + __popcll(hf1);
  uint32_t best = 0xFFFFFFFFu;
  for (int m = m0 + t; m < m1; m += 256) {
    u32x4 pv = reinterpret_cast<const u32x4*>(hm_bits)[m];
    uint64_t h0 = (uint64_t)pv[0] | ((uint64_t)pv[1] << 32);
    uint64_t h1 = (uint64_t)pv[2] | ((uint64_t)pv[3] << 32);
    int hmsum = __popcll(h0) + __popcll(h1);
    int dot   = __popcll(h0 & hf0) + __popcll(h1 & hf1);
    int hd    = hfsum + hmsum - 2 * dot;
    uint32_t key = ((uint32_t)hd << 16) | (uint32_t)m;   // M < 65536, HD <= 256
    best = best < key ? best : key;
  }
  red[t] = best;
  __syncthreads();
  for (int s = 128; s > 0; s >>= 1) {
    if (t < s) red[t] = red[t] < red[t + s] ? red[t] : red[t + s];
    __syncthreads();
  }
  if (t == 0) atomicMin(&keys[b], red[0]);   // device-scope, order-independent
}

// ---- Kernel C: gather nearest memory rows -----------------------------------
__global__ __launch_bounds__(256) void gather_kernel(
    const float* __restrict__ memory, const unsigned int* __restrict__ keys,
    float* __restrict__ out) {
  int b = blockIdx.x;
  int t = threadIdx.x;
  int m = (int)(keys[b] & 0xFFFFu);
  const f32x4* src = reinterpret_cast<const f32x4*>(memory + (size_t)m * KDIM);
  f32x4* dst = reinterpret_cast<f32x4*>(out + (size_t)b * KDIM);
#pragma unroll
  for (int c = 0; c < 4; ++c) dst[t + 256 * c] = src[t + 256 * c];
}

extern "C" void kernel_launch(void* const* d_in, const int* in_sizes, int n_in,
                              void* d_out, int out_size, void* d_ws, size_t ws_size,
                              hipStream_t stream) {
  const float* feature = (const float*)d_in[0];   // [64,64,8,8] == [64,4096]
  const float* memory  = (const float*)d_in[1];   // [50000,4096]
  const float* hash_W  = (const float*)d_in[2];   // [128,4096]
  const float* hash_b  = (const float*)d_in[3];   // [128]
  float* out = (float*)d_out;

  char* ws = (char*)d_ws;
  unsigned short* Wb       = (unsigned short*)ws;                       // 1,048,576 B
  uint32_t*       hm_bits  = (uint32_t*)(ws + 1048576);                 //   800,000 B
  unsigned char*  hf_bytes = (unsigned char*)(ws + 1048576 + 800000);   //     8,192 B
  unsigned int*   keys     = (unsigned int*)(ws + 1048576 + 800000 + 8192); //   256 B

  prep_kernel<<<2560, 256, 0, stream>>>(hash_W, Wb, feature, hash_b, hf_bytes, keys);
  hash_bits_kernel<<<NBLK, 512, 0, stream>>>(memory, Wb, hash_b, hm_bits);
  argmin_part_kernel<<<BFEAT * NSEG, 256, 0, stream>>>(hm_bits, hf_bytes, MMEM, keys);
  gather_kernel<<<BFEAT, 256, 0, stream>>>(memory, keys, out);
}